// Round 3
// baseline (1268.044 us; speedup 1.0000x reference)
//
#include <hip/hip_runtime.h>
#include <cstdint>
#include <cstddef>

typedef __bf16 bf16_t;
typedef __attribute__((ext_vector_type(8))) __bf16 bf16x8;
typedef __attribute__((ext_vector_type(4))) __bf16 bf16x4;
typedef __attribute__((ext_vector_type(16))) float floatx16;

#define SB0 __builtin_amdgcn_sched_barrier(0)
#define LGKM(N)                                             \
  do {                                                      \
    asm volatile("s_waitcnt lgkmcnt(" #N ")" ::: "memory"); \
    SB0;                                                    \
  } while (0)

// ---------------------------------------------------------------------------
// async 16B global -> LDS copy (direct-to-LDS DMA, no VGPR round trip).
__device__ __forceinline__ void cp16(const void* g, void* l) {
  __builtin_amdgcn_global_load_lds(
      (const __attribute__((address_space(1))) void*)(uintptr_t)g,
      (__attribute__((address_space(3))) void*)(uintptr_t)l, 16, 0, 0);
}

// stage one 16 KB half-tile (256 rows x 32 k bf16): 2 issues x 512 thr x 16 B.
__device__ __forceinline__ void stage_half(const bf16_t* p, int K, char* dst,
                                           int tid) {
  cp16(p, dst + tid * 16);
  cp16(p + (size_t)128 * K, dst + 8192 + tid * 16);
}

// ---------------------------------------------------------------------------
// Fused prep: x->bf16 cvt | 4x W^T assembly | 4x bias row. One launch.
struct PrepArgs {
  const float* x;
  bf16_t* xb;
  const float* M[4];
  const float* u[4];
  const float* v[4];
  const float* e[4];
  bf16_t* Wt[4];
  float* bias[4];
};

__global__ __launch_bounds__(256) void prep_all(PrepArgs a) {
  __shared__ float tile[32][33];
  const int tx = threadIdx.x, ty = threadIdx.y;
  const int tid = ty * 32 + tx;
  int bid = blockIdx.x;

  if (bid < 16384) {  // ---- cvt: 8192x2048 fp32 -> bf16, float4-vectorized
    const int i = bid * 256 + tid;
    float4 f = ((const float4*)a.x)[i];
    bf16x4 o;
    o[0] = (bf16_t)f.x; o[1] = (bf16_t)f.y; o[2] = (bf16_t)f.z; o[3] = (bf16_t)f.w;
    ((bf16x4*)a.xb)[i] = o;
    return;
  }
  bid -= 16384;

  if (bid >= 49152) {  // ---- bias rows (56 blocks of 256)
    const int b = bid - 49152;
    int layer, base;
    if (b < 16) { layer = 0; base = b; }
    else if (b < 32) { layer = 1; base = b - 16; }
    else if (b < 48) { layer = 2; base = b - 32; }
    else { layer = 3; base = b - 48; }
    const int K = (layer == 0) ? 2048 : 4096;
    const int N = (layer == 3) ? 2048 : 4096;
    const int n = base * 256 + tid;
    if (n < N) {
      const size_t idx = (size_t)K * N + n;
      a.bias[layer][n] = a.M[layer][idx] +
                         __expf(0.5f * a.u[layer][K]) * a.e[layer][idx] *
                             __expf(0.5f * a.v[layer][n]);
    }
    return;
  }

  // ---- W^T tiles: Wt[n][k] = bf16(M[k][n] + exp(.5u[k])*eps[k][n]*exp(.5v[n]))
  int layer, nbx, kby, K, N;
  if (bid < 8192) { layer = 0; K = 2048; N = 4096; nbx = bid & 127; kby = bid >> 7; }
  else if (bid < 24576) { layer = 1; K = 4096; N = 4096; int b = bid - 8192; nbx = b & 127; kby = b >> 7; }
  else if (bid < 40960) { layer = 2; K = 4096; N = 4096; int b = bid - 24576; nbx = b & 127; kby = b >> 7; }
  else { layer = 3; K = 4096; N = 2048; int b = bid - 40960; nbx = b & 63; kby = b >> 6; }
  const float* M = a.M[layer];
  const float* u = a.u[layer];
  const float* v = a.v[layer];
  const float* eps = a.e[layer];
  bf16_t* Wt = a.Wt[layer];
  const int nb = nbx * 32, kb = kby * 32;
  const float sv = __expf(0.5f * v[nb + tx]);
#pragma unroll
  for (int r = 0; r < 4; ++r) {
    const int k = kb + ty + 8 * r;
    const float su = __expf(0.5f * u[k]);
    const size_t idx = (size_t)k * N + nb + tx;
    tile[ty + 8 * r][tx] = M[idx] + su * eps[idx] * sv;
  }
  __syncthreads();
#pragma unroll
  for (int r = 0; r < 4; ++r) {
    const int n = nb + ty + 8 * r;
    Wt[(size_t)n * K + kb + tx] = (bf16_t)tile[tx][ty + 8 * r];
  }
}

// ---------------------------------------------------------------------------
// 256x256 bf16 GEMM, 32x32x16 MFMA, half-tile read-prefetch.
// 8 waves (2M x 4N), wave tile 128x64 = 4 m-blocks x 2 n-blocks of 32.
// LDS 128 KiB: buf b at b*65536: A halves at +0/+16384 ([256][32] bf16 each),
// B halves at +32768/+49152. XOR swizzle slot^=(row>>1)&3 (both-sides, as R1).
//
// Per tile t (cur=t&1): [stage nxt k1 | rd h0 (12) | lgkm(6) mfma8 |
//   rd h1 (12) | lgkm(12) mfma8 | B1 | stage cur k0(t+2) | lgkm(6) mfma8 |
//   lgkm(0) mfma8 | vmcnt(4) | B2].  lgkm ledger: at lgkm(6) 12 issued ->
//   r1-6 done; at lgkm(12) 24 issued -> r1-12 done (h0 drained before B1);
//   post-B1 lgkm(6) -> r13-18 done; lgkm(0) all. vmcnt(4) leaves t+2-k0.
__device__ __forceinline__ void rd6(const char* HA, const char* HB, int aoff,
                                    int boff, bf16x8 (&af)[4], bf16x8 (&bb)[2]) {
  bb[0] = *(const bf16x8*)(HB + boff);
  bb[1] = *(const bf16x8*)(HB + boff + 2048);
  af[0] = *(const bf16x8*)(HA + aoff);
  af[1] = *(const bf16x8*)(HA + aoff + 2048);
  af[2] = *(const bf16x8*)(HA + aoff + 4096);
  af[3] = *(const bf16x8*)(HA + aoff + 6144);
}

// swapped operands: mfma(bb, af) -> D col(lane&31)=m, row(reg-map)=n.
__device__ __forceinline__ void mf8(const bf16x8 (&af)[4], const bf16x8 (&bb)[2],
                                    floatx16 (&acc)[4][2]) {
  __builtin_amdgcn_s_setprio(1);
#pragma unroll
  for (int mb = 0; mb < 4; ++mb)
#pragma unroll
    for (int nb = 0; nb < 2; ++nb)
      acc[mb][nb] = __builtin_amdgcn_mfma_f32_32x32x16_bf16(
          bb[nb], af[mb], acc[mb][nb], 0, 0, 0);
  __builtin_amdgcn_s_setprio(0);
}

template <int CURB>
__device__ __forceinline__ void ktile(int t, int NT, int K, const bf16_t* gA,
                                      const bf16_t* gB, char* lds, int tid,
                                      int aoff0, int aoff1, int boff0, int boff1,
                                      floatx16 (&acc)[4][2]) {
  constexpr int curO = CURB * 65536;
  constexpr int nxtO = (CURB ^ 1) * 65536;
  const char* A0 = lds + curO;
  const char* A1 = lds + curO + 16384;
  const char* B0 = lds + curO + 32768;
  const char* B1h = lds + curO + 49152;
  bf16x8 afX[4], bbX[2], afY[4], bbY[2], afZ[4], bbZ[2];

  // stage t+1's k1 halves into nxt (nxt fully consumed in tile t-1)
  if (t + 1 < NT) {
    stage_half(gA + (size_t)(t + 1) * 64 + 32, K, lds + nxtO + 16384, tid);
    stage_half(gB + (size_t)(t + 1) * 64 + 32, K, lds + nxtO + 49152, tid);
  }
  rd6(A0, B0, aoff0, boff0, afX, bbX);
  SB0;
  rd6(A0, B0, aoff1, boff1, afY, bbY);
  SB0;
  LGKM(6);
  mf8(afX, bbX, acc);
  rd6(A1, B1h, aoff0, boff0, afZ, bbZ);
  SB0;
  rd6(A1, B1h, aoff1, boff1, afX, bbX);
  SB0;
  LGKM(12);  // h0 fully drained (<=12 outstanding = h1's reads)
  mf8(afY, bbY, acc);
  SB0;
  __builtin_amdgcn_s_barrier();  // B1: all waves done reading kk0
  SB0;
  // stage t+2's k0 halves into cur-kk0 (retired at B1)
  if (t + 2 < NT) {
    stage_half(gA + (size_t)(t + 2) * 64, K, lds + curO, tid);
    stage_half(gB + (size_t)(t + 2) * 64, K, lds + curO + 32768, tid);
  }
  LGKM(6);
  mf8(afZ, bbZ, acc);
  LGKM(0);
  mf8(afX, bbX, acc);
  SB0;
  // counted vmcnt: never 0 in steady state. 4 loads = t+2's k0 halves.
  if (t + 2 < NT) {
    asm volatile("s_waitcnt vmcnt(4)" ::: "memory");
  } else if (t + 1 < NT) {
    asm volatile("s_waitcnt vmcnt(0)" ::: "memory");
  }
  SB0;
  __builtin_amdgcn_s_barrier();  // B2: tile t+1 published
  SB0;
}

template <int EPI>
__global__ __launch_bounds__(512, 2) void gemm256(
    const bf16_t* __restrict__ A, const bf16_t* __restrict__ Bt,
    const float* __restrict__ bias, void* __restrict__ Cout, int N, int K) {
  extern __shared__ char lds[];
  const int tid = threadIdx.x;
  const int lane = tid & 63;
  const int wave = tid >> 6;
  const int wm = (wave >> 2) * 128;  // 2 M-waves
  const int wn = (wave & 3) * 64;    // 4 N-waves

  // 32x32x16 operand frags: lane&31 = row, lane>>5 = k-half (8 bf16).
  // byte off in [256][32] half: row*64 + (slot ^ ((row>>1)&3))*16,
  // slot = klo*2 + (lane>>5).
  const int l31 = lane & 31;
  const int kh = lane >> 5;
  const int lA = wm + l31;
  const int lB = wn + l31;
  const int xA = (lA >> 1) & 3;
  const int xB = (lB >> 1) & 3;
  const int aoff0 = lA * 64 + ((kh ^ xA) << 4);
  const int aoff1 = lA * 64 + (((2 + kh) ^ xA) << 4);
  const int boff0 = lB * 64 + ((kh ^ xB) << 4);
  const int boff1 = lB * 64 + (((2 + kh) ^ xB) << 4);

  // XCD-aware bijective swizzle (nwg % 8 == 0 for all our grids)
  const int gx = gridDim.x;
  int id = blockIdx.y * gx + blockIdx.x;
  const int cpx = (gx * (int)gridDim.y) >> 3;
  id = (id & 7) * cpx + (id >> 3);
  const int bm = (id / gx) * 256;
  const int bn = (id % gx) * 256;

  // staging source: row tid>>2 (+128 for 2nd issue), inverse-swizzled k-slot
  const int srow = tid >> 2;
  const int ss8 = ((tid & 3) ^ ((tid >> 3) & 3)) * 8;
  const bf16_t* gA = A + (size_t)(bm + srow) * K + ss8;
  const bf16_t* gB = Bt + (size_t)(bn + srow) * K + ss8;

  const int NT = K >> 6;  // 32 or 64, always even

  floatx16 acc[4][2] = {};

  // ---- prologue: tile0 (4 halves) + tile1 k0 halves; vmcnt(4) leaves t1-k0
  stage_half(gA, K, lds + 0, tid);
  stage_half(gA + 32, K, lds + 16384, tid);
  stage_half(gB, K, lds + 32768, tid);
  stage_half(gB + 32, K, lds + 49152, tid);
  stage_half(gA + 64, K, lds + 65536, tid);
  stage_half(gB + 64, K, lds + 65536 + 32768, tid);
  asm volatile("s_waitcnt vmcnt(4)" ::: "memory");
  __builtin_amdgcn_s_barrier();
  SB0;

  for (int t = 0; t < NT; t += 2) {
    ktile<0>(t, NT, K, gA, gB, lds, tid, aoff0, aoff1, boff0, boff1, acc);
    ktile<1>(t + 1, NT, K, gA, gB, lds, tid, aoff0, aoff1, boff0, boff1, acc);
  }

  // epilogue: acc[mb][nb] reg r, lane l -> C[bm+wm+mb*32+(l&31)]
  //   [bn+wn+nb*32 + (r&3) + 8*(r>>2) + 4*(l>>5)]  (swapped-operand D map)
  const int m0 = bm + wm + l31;
  const int kh4 = kh * 4;
#pragma unroll
  for (int nb = 0; nb < 2; ++nb) {
#pragma unroll
    for (int q = 0; q < 4; ++q) {
      const int col = bn + wn + nb * 32 + q * 8 + kh4;
      const float4 b4 = *(const float4*)&bias[col];
#pragma unroll
      for (int mb = 0; mb < 4; ++mb) {
        float x0 = acc[mb][nb][q * 4 + 0] + b4.x;
        float x1 = acc[mb][nb][q * 4 + 1] + b4.y;
        float x2 = acc[mb][nb][q * 4 + 2] + b4.z;
        float x3 = acc[mb][nb][q * 4 + 3] + b4.w;
        const size_t idx = (size_t)(m0 + mb * 32) * N + col;
        if (EPI == 0) {
          x0 = fmaxf(x0, 0.f);
          x1 = fmaxf(x1, 0.f);
          x2 = fmaxf(x2, 0.f);
          x3 = fmaxf(x3, 0.f);
          bf16x4 o;
          o[0] = (bf16_t)x0; o[1] = (bf16_t)x1; o[2] = (bf16_t)x2; o[3] = (bf16_t)x3;
          *(bf16x4*)((bf16_t*)Cout + idx) = o;
        } else {
          *(float4*)((float*)Cout + idx) = make_float4(x0, x1, x2, x3);
        }
      }
    }
  }
}

// ---------------------------------------------------------------------------
extern "C" void kernel_launch(void* const* d_in, const int* in_sizes, int n_in,
                              void* d_out, int out_size, void* d_ws, size_t ws_size,
                              hipStream_t stream) {
  const float* x = (const float*)d_in[0];
  const float *Mm[4], *uu[4], *vv[4], *ee[4];
  for (int i = 0; i < 4; ++i) {
    Mm[i] = (const float*)d_in[1 + 4 * i];
    uu[i] = (const float*)d_in[2 + 4 * i];
    vv[i] = (const float*)d_in[3 + 4 * i];
    ee[i] = (const float*)d_in[4 + 4 * i];
  }

  // workspace layout (≈224 MiB):
  //   Wt0 [4096,2048] bf16 | Wt1 [4096,4096] | Wt2 [4096,4096] | Wt3 [2048,4096]
  //   bias0..3 fp32 | hA (8192x4096 bf16) | hB (8192x4096 bf16)
  char* ws = (char*)d_ws;
  bf16_t* Wt0 = (bf16_t*)ws;
  bf16_t* Wt1 = (bf16_t*)(ws + 16777216);
  bf16_t* Wt2 = (bf16_t*)(ws + 16777216 + 33554432);
  bf16_t* Wt3 = (bf16_t*)(ws + 16777216 + 2u * 33554432);
  char* bptr = ws + 2u * 16777216 + 2u * 33554432;
  float* bias0 = (float*)(bptr);
  float* bias1 = (float*)(bptr + 16384);
  float* bias2 = (float*)(bptr + 32768);
  float* bias3 = (float*)(bptr + 49152);
  char* act = bptr + 65536;
  bf16_t* hA = (bf16_t*)act;
  bf16_t* hB = (bf16_t*)(act + 67108864);
  bf16_t* xb = (bf16_t*)d_out;  // dead until final GEMM overwrites d_out

  static bool attr_set = false;
  if (!attr_set) {
    (void)hipFuncSetAttribute(reinterpret_cast<const void*>(&gemm256<0>),
                              hipFuncAttributeMaxDynamicSharedMemorySize, 131072);
    (void)hipFuncSetAttribute(reinterpret_cast<const void*>(&gemm256<1>),
                              hipFuncAttributeMaxDynamicSharedMemorySize, 131072);
    attr_set = true;
  }

  // --- fused prep: 1 launch (cvt 16384 | wt 49152 | bias 56) ---
  PrepArgs pa;
  pa.x = x;
  pa.xb = xb;
  for (int i = 0; i < 4; ++i) {
    pa.M[i] = Mm[i]; pa.u[i] = uu[i]; pa.v[i] = vv[i]; pa.e[i] = ee[i];
  }
  pa.Wt[0] = Wt0; pa.Wt[1] = Wt1; pa.Wt[2] = Wt2; pa.Wt[3] = Wt3;
  pa.bias[0] = bias0; pa.bias[1] = bias1; pa.bias[2] = bias2; pa.bias[3] = bias3;
  prep_all<<<16384 + 49152 + 56, dim3(32, 8), 0, stream>>>(pa);

  // --- chained GEMMs: 256^2, 32x32x16 MFMA, half-tile read-prefetch ---
  gemm256<0><<<dim3(16, 32), 512, 131072, stream>>>(xb, Wt0, bias0, hA, 4096, 2048);
  gemm256<0><<<dim3(16, 32), 512, 131072, stream>>>(hA, Wt1, bias1, hB, 4096, 4096);
  gemm256<0><<<dim3(16, 32), 512, 131072, stream>>>(hB, Wt2, bias2, hA, 4096, 4096);
  gemm256<1><<<dim3(8, 32), 512, 131072, stream>>>(hA, Wt3, bias3, d_out, 2048, 4096);
}